// Round 1
// baseline (1348.502 us; speedup 1.0000x reference)
//
#include <hip/hip_runtime.h>
#include <cstdint>
#include <math.h>

// Problem constants
#define NMC   16
#define SDIM  4
#define ODIM  3
#define TLEN  128
#define BDIM  256
#define MDIM  32
#define HLDIM 64
#define PARD  36

#define LOG2PI_F 1.8378770664093453f

// ---------------------------------------------------------------------------
// threefry2x32 (JAX-compatible, 20 rounds)
// ---------------------------------------------------------------------------
__host__ __device__ inline void threefry2x32(uint32_t k0, uint32_t k1,
                                             uint32_t x0, uint32_t x1,
                                             uint32_t* o0, uint32_t* o1) {
  uint32_t ks0 = k0, ks1 = k1, ks2 = k0 ^ k1 ^ 0x1BD11BDAu;
  x0 += ks0; x1 += ks1;
#define TF_R(r) { x0 += x1; x1 = (x1 << (r)) | (x1 >> (32 - (r))); x1 ^= x0; }
  TF_R(13) TF_R(15) TF_R(26) TF_R(6)  x0 += ks1; x1 += ks2 + 1u;
  TF_R(17) TF_R(29) TF_R(16) TF_R(24) x0 += ks2; x1 += ks0 + 2u;
  TF_R(13) TF_R(15) TF_R(26) TF_R(6)  x0 += ks0; x1 += ks1 + 3u;
  TF_R(17) TF_R(29) TF_R(16) TF_R(24) x0 += ks1; x1 += ks2 + 4u;
  TF_R(13) TF_R(15) TF_R(26) TF_R(6)  x0 += ks2; x1 += ks0 + 5u;
#undef TF_R
  *o0 = x0; *o1 = x1;
}

// XLA f32 ErfInv polynomial (Giles)
__device__ inline float erfinv_f32(float x) {
  float w = -log1pf(-x * x);
  float p;
  if (w < 5.0f) {
    w -= 2.5f;
    p = 2.81022636e-08f;
    p = fmaf(p, w, 3.43273939e-07f);
    p = fmaf(p, w, -3.5233877e-06f);
    p = fmaf(p, w, -4.39150654e-06f);
    p = fmaf(p, w, 0.00021858087f);
    p = fmaf(p, w, -0.00125372503f);
    p = fmaf(p, w, -0.00417768164f);
    p = fmaf(p, w, 0.246640727f);
    p = fmaf(p, w, 1.50140941f);
  } else {
    w = sqrtf(w) - 3.0f;
    p = -0.000200214257f;
    p = fmaf(p, w, 0.000100950558f);
    p = fmaf(p, w, 0.00134934322f);
    p = fmaf(p, w, -0.00367342844f);
    p = fmaf(p, w, 0.00573950773f);
    p = fmaf(p, w, -0.0076224613f);
    p = fmaf(p, w, 0.00943887047f);
    p = fmaf(p, w, 1.00167406f);
    p = fmaf(p, w, 2.83297682f);
  }
  return p * x;
}

__device__ inline float bits_to_normal(uint32_t b) {
  float f = __uint_as_float((b >> 9) | 0x3F800000u) - 1.0f;  // [0,1)
  const float lo = -0.99999994f;
  float u = f * 2.0f + lo;   // (hi-lo) folds to 2.0f in f32, same as XLA
  u = fmaxf(lo, u);
  return 1.41421356f * erfinv_f32(u);
}

// out[j] / out[j+nhalf] from counter pair (j, j+nhalf) — matches JAX concat
__global__ void rng_kernel(uint32_t ka, uint32_t kb, uint32_t nhalf, float* out) {
  uint32_t j = blockIdx.x * blockDim.x + threadIdx.x;
  if (j >= nhalf) return;
  uint32_t o0, o1;
  threefry2x32(ka, kb, j, j + nhalf, &o0, &o1);
  out[j] = bits_to_normal(o0);
  out[j + nhalf] = bits_to_normal(o1);
}

// ---------------------------------------------------------------------------
// LSTM encoder: one block per batch row b; 256 threads (one per gate-row).
// Thread r holds Whh row r in registers; h (64) exchanged via LDS.
// Produces m0, v0 and qm0_KL partial (acc[0]).
// ---------------------------------------------------------------------------
__global__ __launch_bounds__(256) void lstm_kernel(
    const float* __restrict__ obs, const float* __restrict__ Wih,
    const float* __restrict__ Whh, const float* __restrict__ b_lstm,
    const float* __restrict__ Wm, const float* __restrict__ bm,
    const float* __restrict__ Wv, const float* __restrict__ bv,
    float* __restrict__ m0_g, float* __restrict__ v0_g, float* __restrict__ acc) {
  __shared__ float h_l[64];
  __shared__ float g_l[256];
  __shared__ float mv_l[8];
  const int tid = threadIdx.x;
  const int b = blockIdx.x;

  float whh_r[64];
#pragma unroll
  for (int k = 0; k < 64; ++k) whh_r[k] = Whh[tid * 64 + k];
  const float wih0 = Wih[tid * 3 + 0];
  const float wih1 = Wih[tid * 3 + 1];
  const float wih2 = Wih[tid * 3 + 2];
  const float bb = b_lstm[tid];

  float c_ = 0.0f;
  if (tid < 64) h_l[tid] = 0.0f;
  __syncthreads();

  const float* ob = obs + b * TLEN * ODIM;
#pragma unroll 1
  for (int t = 0; t < TLEN; ++t) {
    const float x0 = ob[t * 3 + 0], x1 = ob[t * 3 + 1], x2 = ob[t * 3 + 2];
    float a0 = 0.f, a1 = 0.f, a2 = 0.f, a3 = 0.f;
#pragma unroll
    for (int k = 0; k < 64; k += 4) {
      a0 = fmaf(whh_r[k + 0], h_l[k + 0], a0);
      a1 = fmaf(whh_r[k + 1], h_l[k + 1], a1);
      a2 = fmaf(whh_r[k + 2], h_l[k + 2], a2);
      a3 = fmaf(whh_r[k + 3], h_l[k + 3], a3);
    }
    float g = bb + wih0 * x0 + wih1 * x1 + wih2 * x2 + ((a0 + a1) + (a2 + a3));
    g_l[tid] = g;
    __syncthreads();
    if (tid < 64) {
      float ig = 1.0f / (1.0f + expf(-g_l[tid]));
      float fg = 1.0f / (1.0f + expf(-g_l[64 + tid]));
      float gg = tanhf(g_l[128 + tid]);
      float og = 1.0f / (1.0f + expf(-g_l[192 + tid]));
      c_ = fg * c_ + ig * gg;
      h_l[tid] = og * tanhf(c_);
    }
    __syncthreads();
  }

  // m0 / v0 / qm0_KL partial
  if (tid < 8) {
    const int s = tid & 3;
    const bool isv = tid >= 4;
    const float* W = isv ? (Wv + s * 64) : (Wm + s * 64);
    float a = isv ? bv[s] : bm[s];
#pragma unroll
    for (int k = 0; k < 64; ++k) a += W[k] * h_l[k];
    if (!isv) {
      m0_g[b * 4 + s] = a;
      mv_l[s] = a;
    } else {
      float sp = (a > 0.f) ? (a + log1pf(expf(-a))) : log1pf(expf(a));
      float v = sp + 1e-6f;
      v0_g[b * 4 + s] = v;
      mv_l[4 + s] = v;
    }
  }
  __syncthreads();
  if (tid == 0) {
    float s = 0.f;
#pragma unroll
    for (int k = 0; k < 4; ++k) {
      float m = mv_l[k], v = mv_l[4 + k];
      s += 0.5f * (v + m * m - 1.0f - logf(v));
    }
    atomicAdd(&acc[0], s);
  }
}

// ---------------------------------------------------------------------------
// MLP: par = MLP(obs) per (b,t) row. 16 rows per block of 256 threads.
// ---------------------------------------------------------------------------
__global__ __launch_bounds__(256) void mlp_kernel(
    const float* __restrict__ obs, const float* __restrict__ W1, const float* __restrict__ b1,
    const float* __restrict__ W2, const float* __restrict__ b2,
    const float* __restrict__ W3, const float* __restrict__ b3,
    const float* __restrict__ W4, const float* __restrict__ b4,
    float* __restrict__ par_g) {
  __shared__ float xr[16][4];
  __shared__ float h1[16][256];
  __shared__ float h2[16][128];
  __shared__ float h3[16][64];
  const int tid = threadIdx.x;
  const int R0 = blockIdx.x * 16;

  if (tid < 48) {
    int r = tid / 3, o = tid - r * 3;
    xr[r][o] = obs[(R0 + r) * 3 + o];
  }
  __syncthreads();
  {
    const float w0 = W1[tid * 3 + 0], w1 = W1[tid * 3 + 1], w2 = W1[tid * 3 + 2];
    const float bbv = b1[tid];
#pragma unroll
    for (int r = 0; r < 16; ++r) {
      float v = bbv + w0 * xr[r][0] + w1 * xr[r][1] + w2 * xr[r][2];
      h1[r][tid] = fmaxf(v, 0.0f);
    }
  }
  __syncthreads();
  {
    const int j = tid & 127;
    const int r0 = (tid >> 7) * 8;
    const float4* w = (const float4*)(W2 + j * 256);
    const float bbv = b2[j];
    for (int rr = 0; rr < 8; ++rr) {
      const int r = r0 + rr;
      const float4* hv = (const float4*)&h1[r][0];
      float a = bbv;
#pragma unroll 8
      for (int q = 0; q < 64; ++q) {
        float4 wv = w[q], xv = hv[q];
        a += wv.x * xv.x + wv.y * xv.y + wv.z * xv.z + wv.w * xv.w;
      }
      h2[r][j] = fmaxf(a, 0.0f);
    }
  }
  __syncthreads();
  {
    const int j = tid & 63;
    const int r0 = (tid >> 6) * 4;
    const float4* w = (const float4*)(W3 + j * 128);
    const float bbv = b3[j];
    for (int rr = 0; rr < 4; ++rr) {
      const int r = r0 + rr;
      const float4* hv = (const float4*)&h2[r][0];
      float a = bbv;
#pragma unroll 8
      for (int q = 0; q < 32; ++q) {
        float4 wv = w[q], xv = hv[q];
        a += wv.x * xv.x + wv.y * xv.y + wv.z * xv.z + wv.w * xv.w;
      }
      h3[r][j] = fmaxf(a, 0.0f);
    }
  }
  __syncthreads();
  for (int idx = tid; idx < 16 * PARD; idx += 256) {
    const int r = idx / PARD;
    const int p = idx - r * PARD;
    const float4* w = (const float4*)(W4 + p * 64);
    const float4* hv = (const float4*)&h3[r][0];
    float a = b4[p];
#pragma unroll
    for (int q = 0; q < 16; ++q) {
      float4 wv = w[q], xv = hv[q];
      a += wv.x * xv.x + wv.y * xv.y + wv.z * xv.z + wv.w * xv.w;
    }
    par_g[(R0 + r) * PARD + p] = a;
  }
}

// ---------------------------------------------------------------------------
// Setup: per d (4 blocks, 64 threads): Kzz -> chol L -> Kinv; U -> alpha;
// gpKL partial (acc[1]).
// ---------------------------------------------------------------------------
__global__ __launch_bounds__(64) void setup_kernel(
    const float* __restrict__ Z, const float* __restrict__ log_ls,
    const float* __restrict__ log_os, const float* __restrict__ m_u,
    const float* __restrict__ L_u, const float* __restrict__ epsU,
    float* __restrict__ Kinv_g, float* __restrict__ alpha_g, float* __restrict__ acc) {
  const int d = blockIdx.x;
  const int tid = threadIdx.x;
  __shared__ float Kl[32][33];
  __shared__ float work[32][33];
  __shared__ float Ul[16][32];
  __shared__ float bql[32];
  __shared__ float red[64];

  float il[4];
#pragma unroll
  for (int k = 0; k < 4; ++k) il[k] = expf(-log_ls[d * 4 + k]);
  const float osd = expf(log_os[d]);

  for (int e = tid; e < 1024; e += 64) {
    int i = e >> 5, j = e & 31;
    float s = 0.f;
#pragma unroll
    for (int k = 0; k < 4; ++k) {
      float t_ = (Z[d * 128 + i * 4 + k] - Z[d * 128 + j * 4 + k]) * il[k];
      s += t_ * t_;
    }
    float v = osd * expf(-0.5f * s);
    if (i == j) v += 1e-5f;
    Kl[i][j] = v;
  }
  __syncthreads();

  // Cholesky (lower), in place
  for (int jc = 0; jc < 32; ++jc) {
    if (tid == jc) {
      float s = Kl[jc][jc];
      for (int p = 0; p < jc; ++p) s -= Kl[jc][p] * Kl[jc][p];
      Kl[jc][jc] = sqrtf(s);
    }
    __syncthreads();
    if (tid > jc && tid < 32) {
      float s = Kl[tid][jc];
      for (int p = 0; p < jc; ++p) s -= Kl[tid][p] * Kl[jc][p];
      Kl[tid][jc] = s / Kl[jc][jc];
    }
    __syncthreads();
  }

  // Kinv column per thread (fwd then bwd solve, in place in work[col][*])
  if (tid < 32) {
    const int col = tid;
    for (int r = 0; r < 32; ++r) {
      if (r < col) { work[col][r] = 0.f; continue; }
      float s = (r == col) ? 1.f : 0.f;
      for (int p = col; p < r; ++p) s -= Kl[r][p] * work[col][p];
      work[col][r] = s / Kl[r][r];
    }
    for (int r = 31; r >= 0; --r) {
      float s = work[col][r];
      for (int p = r + 1; p < 32; ++p) s -= Kl[p][r] * work[col][p];
      work[col][r] = s / Kl[r][r];
    }
    for (int r = 0; r < 32; ++r) Kinv_g[(d * 32 + r) * 32 + col] = work[col][r];
  }
  // U[n][m] = m_u + tril(L_u) @ epsU
  for (int e = tid; e < 512; e += 64) {
    int nn = e >> 5, m = e & 31;
    float s = m_u[d * 32 + m];
    for (int k = 0; k <= m; ++k)
      s += L_u[(d * 32 + m) * 32 + k] * epsU[(nn * 4 + d) * 32 + k];
    Ul[nn][m] = s;
  }
  __syncthreads();
  // alpha = Kinv @ U  (Kinv[m][mm] == work[mm][m])
  for (int e = tid; e < 512; e += 64) {
    int nn = e >> 5, m = e & 31;
    float s = 0.f;
    for (int mm = 0; mm < 32; ++mm) s += work[mm][m] * Ul[nn][mm];
    alpha_g[(d * 16 + nn) * 32 + m] = s;
  }
  __syncthreads();

  // gpKL pieces: A = L^{-1} tril(L_u) (col per thread), bq = L^{-1} m_u
  float contrib = 0.f;
  if (tid < 32) {
    const int col = tid;
    float sa = 0.f;
    for (int r = 0; r < 32; ++r) {
      float s = (col <= r) ? L_u[(d * 32 + r) * 32 + col] : 0.f;
      for (int p = 0; p < r; ++p) s -= Kl[r][p] * work[col][p];
      float v = s / Kl[r][r];
      work[col][r] = v;
      sa += v * v;
    }
    contrib = sa;
  } else if (tid == 32) {
    float sb = 0.f;
    for (int r = 0; r < 32; ++r) {
      float s = m_u[d * 32 + r];
      for (int p = 0; p < r; ++p) s -= Kl[r][p] * bql[p];
      float v = s / Kl[r][r];
      bql[r] = v;
      sb += v * v;
    }
    contrib = sb;
  }
  red[tid] = contrib;
  __syncthreads();
  if (tid == 0) {
    float s = 0.f;
    for (int i = 0; i < 64; ++i) s += red[i];
    float ldK = 0.f, ldS = 0.f;
    for (int r = 0; r < 32; ++r) {
      ldK += logf(Kl[r][r]);
      ldS += logf(fabsf(L_u[(d * 32 + r) * 32 + r]) + 1e-12f);
    }
    float g = s - 32.0f + 2.0f * ldK - 2.0f * ldS;
    atomicAdd(&acc[1], 0.5f * g / (128.0f * 256.0f));
  }
}

// ---------------------------------------------------------------------------
// Scan: 4096 independent chains (n,b); 32 lanes per chain (lane = m);
// 8 chains per block sharing b. Kinv rows in registers; k exchanged via LDS.
// Accumulates KL (acc[2]) and lik (acc[3]) sums.
// ---------------------------------------------------------------------------
__global__ __launch_bounds__(256, 2) void scan_kernel(
    const float* __restrict__ Z, const float* __restrict__ log_ls,
    const float* __restrict__ log_os, const float* __restrict__ noise_proc,
    const float* __restrict__ noise_emis, const float* __restrict__ obs,
    const float* __restrict__ par_g, const float* __restrict__ m0_g,
    const float* __restrict__ v0_g, const float* __restrict__ eps0,
    const float* __restrict__ epsq, const float* __restrict__ Kinv_g,
    const float* __restrict__ alpha_g, float* __restrict__ acc) {
  __shared__ float kbuf[8][4][32];
  const int tid = threadIdx.x;
  const int c = tid >> 5;        // chain in block
  const int m = tid & 31;        // inducing point index
  const int b = blockIdx.x >> 1;
  const int n = ((blockIdx.x & 1) << 3) + c;

  // Per-lane constants
  float zr[4][4], ilr[4][4], osr[4];
#pragma unroll
  for (int d = 0; d < 4; ++d) {
#pragma unroll
    for (int k = 0; k < 4; ++k) {
      zr[d][k] = Z[d * 128 + m * 4 + k];
      ilr[d][k] = expf(-log_ls[d * 4 + k]);
    }
    osr[d] = expf(log_os[d]);
  }
  float kinv[4][32];
  {
    const float4* kg4 = (const float4*)Kinv_g;
#pragma unroll
    for (int d = 0; d < 4; ++d) {
#pragma unroll
      for (int q = 0; q < 8; ++q) {
        float4 v = kg4[(d * 32 + m) * 8 + q];
        kinv[d][q * 4 + 0] = v.x;
        kinv[d][q * 4 + 1] = v.y;
        kinv[d][q * 4 + 2] = v.z;
        kinv[d][q * 4 + 3] = v.w;
      }
    }
  }
  float alr[4];
#pragma unroll
  for (int d = 0; d < 4; ++d) alr[d] = alpha_g[(d * 16 + n) * 32 + m];
  float np_[4];
#pragma unroll
  for (int k = 0; k < 4; ++k) np_[k] = noise_proc[k];
  float ine0 = 1.0f / noise_emis[0], ine1 = 1.0f / noise_emis[1], ine2 = 1.0f / noise_emis[2];
  const float cst = 3.0f * LOG2PI_F + logf(noise_emis[0]) + logf(noise_emis[1]) + logf(noise_emis[2]);

  const float* parb = par_g + b * TLEN * PARD;
  const float* obsb = obs + b * TLEN * ODIM;

  float x0r = 0.f, x1r = 0.f, x2r = 0.f, x3r = 0.f;
  float kl_acc = 0.f, ell_acc = 0.f;

#pragma unroll 1
  for (int t = 0; t < TLEN; ++t) {
    // Hoisted uniform loads for this step (latency hidden behind phases)
    const float4* pv = (const float4*)(parb + t * PARD);
    const float4 a0 = pv[0], a1 = pv[1], a2 = pv[2], a3 = pv[3];
    const float4 btv = pv[4];
    const float4 s0 = pv[5], s1 = pv[6], s2 = pv[7], s3 = pv[8];
    const float y0 = obsb[t * 3 + 0], y1 = obsb[t * 3 + 1], y2 = obsb[t * 3 + 2];
    const float4 ev = *(const float4*)(epsq + (((t * 16 + n) * 256 + b) << 2));

    // ---- phase 1: RBF features k_m per output dim d ----
    float kreg[4];
#pragma unroll
    for (int d = 0; d < 4; ++d) {
      float xt0, xt1, xt2, xt3;
      if (t == 0) {
        const int e0i = ((n * 4 + d) * 256 + b) * 4;
        xt0 = m0_g[b * 4 + 0] + sqrtf(v0_g[b * 4 + 0]) * eps0[e0i + 0];
        xt1 = m0_g[b * 4 + 1] + sqrtf(v0_g[b * 4 + 1]) * eps0[e0i + 1];
        xt2 = m0_g[b * 4 + 2] + sqrtf(v0_g[b * 4 + 2]) * eps0[e0i + 2];
        xt3 = m0_g[b * 4 + 3] + sqrtf(v0_g[b * 4 + 3]) * eps0[e0i + 3];
      } else {
        xt0 = x0r; xt1 = x1r; xt2 = x2r; xt3 = x3r;
      }
      float d0_ = (xt0 - zr[d][0]) * ilr[d][0];
      float d1_ = (xt1 - zr[d][1]) * ilr[d][1];
      float d2_ = (xt2 - zr[d][2]) * ilr[d][2];
      float d3_ = (xt3 - zr[d][3]) * ilr[d][3];
      float ss = d0_ * d0_ + d1_ * d1_ + d2_ * d2_ + d3_ * d3_;
      float km = osr[d] * __expf(-0.5f * ss);
      kreg[d] = km;
      kbuf[c][d][m] = km;
    }
    __syncthreads();

    // ---- phase 2: mean_d = k.alpha ; quad_d = k^T Kinv k ----
    float gm[4], gv[4];
#pragma unroll
    for (int d = 0; d < 4; ++d) {
      const float4* kb4 = (const float4*)&kbuf[c][d][0];
      float ya = 0.f, yb = 0.f, yc = 0.f, yd = 0.f;
#pragma unroll
      for (int q = 0; q < 8; ++q) {
        float4 kv = kb4[q];
        ya = fmaf(kinv[d][q * 4 + 0], kv.x, ya);
        yb = fmaf(kinv[d][q * 4 + 1], kv.y, yb);
        yc = fmaf(kinv[d][q * 4 + 2], kv.z, yc);
        yd = fmaf(kinv[d][q * 4 + 3], kv.w, yd);
      }
      float y = (ya + yb) + (yc + yd);
      float mp = kreg[d] * alr[d];
      float qp = kreg[d] * y;
#pragma unroll
      for (int off = 16; off >= 1; off >>= 1) {
        mp += __shfl_xor(mp, off, 32);
        qp += __shfl_xor(qp, off, 32);
      }
      gm[d] = mp;
      gv[d] = fmaxf(osr[d] - qp, 1e-8f);
    }
    __syncthreads();  // kbuf reuse next step

    // ---- tail (redundant on all 32 lanes of the chain) ----
    float qm0 = btv.x + a0.x * gm[0] + a0.y * gm[1] + a0.z * gm[2] + a0.w * gm[3];
    float qm1 = btv.y + a1.x * gm[0] + a1.y * gm[1] + a1.z * gm[2] + a1.w * gm[3];
    float qm2 = btv.z + a2.x * gm[0] + a2.y * gm[1] + a2.z * gm[2] + a2.w * gm[3];
    float qm3 = btv.w + a3.x * gm[0] + a3.y * gm[1] + a3.z * gm[2] + a3.w * gm[3];

    // St = tril(Stl) tril(Stl)^T  (lower)
    float St00 = s0.x * s0.x;
    float St10 = s1.x * s0.x;
    float St11 = s1.x * s1.x + s1.y * s1.y;
    float St20 = s2.x * s0.x;
    float St21 = s2.x * s1.x + s2.y * s1.y;
    float St22 = s2.x * s2.x + s2.y * s2.y + s2.z * s2.z;
    float St30 = s3.x * s0.x;
    float St31 = s3.x * s1.x + s3.y * s1.y;
    float St32 = s3.x * s2.x + s3.y * s2.y + s3.z * s2.z;
    float St33 = s3.x * s3.x + s3.y * s3.y + s3.z * s3.z + s3.w * s3.w;

    // A diag(gv) A^T
    float w0x = a0.x * gv[0], w0y = a0.y * gv[1], w0z = a0.z * gv[2], w0w = a0.w * gv[3];
    float w1x = a1.x * gv[0], w1y = a1.y * gv[1], w1z = a1.z * gv[2], w1w = a1.w * gv[3];
    float w2x = a2.x * gv[0], w2y = a2.y * gv[1], w2z = a2.z * gv[2], w2w = a2.w * gv[3];
    float w3x = a3.x * gv[0], w3y = a3.y * gv[1], w3z = a3.z * gv[2], w3w = a3.w * gv[3];
    float qc00 = St00 + w0x * a0.x + w0y * a0.y + w0z * a0.z + w0w * a0.w;
    float qc10 = St10 + w1x * a0.x + w1y * a0.y + w1z * a0.z + w1w * a0.w;
    float qc11 = St11 + w1x * a1.x + w1y * a1.y + w1z * a1.z + w1w * a1.w;
    float qc20 = St20 + w2x * a0.x + w2y * a0.y + w2z * a0.z + w2w * a0.w;
    float qc21 = St21 + w2x * a1.x + w2y * a1.y + w2z * a1.z + w2w * a1.w;
    float qc22 = St22 + w2x * a2.x + w2y * a2.y + w2z * a2.z + w2w * a2.w;
    float qc30 = St30 + w3x * a0.x + w3y * a0.y + w3z * a0.z + w3w * a0.w;
    float qc31 = St31 + w3x * a1.x + w3y * a1.y + w3z * a1.z + w3w * a1.w;
    float qc32 = St32 + w3x * a2.x + w3y * a2.y + w3z * a2.z + w3w * a2.w;
    float qc33 = St33 + w3x * a3.x + w3y * a3.y + w3z * a3.z + w3w * a3.w;

    // Cholesky of q_cov + 1e-6 I
    float l00 = sqrtf(qc00 + 1e-6f);
    float i0 = 1.0f / l00;
    float l10 = qc10 * i0, l20 = qc20 * i0, l30 = qc30 * i0;
    float l11 = sqrtf(qc11 + 1e-6f - l10 * l10);
    float i1 = 1.0f / l11;
    float l21 = (qc21 - l20 * l10) * i1;
    float l31 = (qc31 - l30 * l10) * i1;
    float l22 = sqrtf(qc22 + 1e-6f - l20 * l20 - l21 * l21);
    float i2 = 1.0f / l22;
    float l32 = (qc32 - l30 * l20 - l31 * l21) * i2;
    float l33 = sqrtf(qc33 + 1e-6f - l30 * l30 - l31 * l31 - l32 * l32);
    float logdet_q = 2.0f * logf(l00 * l11 * l22 * l33);

    float dp0 = gv[0] + np_[0], dp1 = gv[1] + np_[1];
    float dp2 = gv[2] + np_[2], dp3 = gv[3] + np_[3];
    float e0 = gm[0] - qm0, e1 = gm[1] - qm1, e2 = gm[2] - qm2, e3 = gm[3] - qm3;
    float klsum = (qc00 + e0 * e0) / dp0 + (qc11 + e1 * e1) / dp1 +
                  (qc22 + e2 * e2) / dp2 + (qc33 + e3 * e3) / dp3;
    float kl = 0.5f * (klsum - 4.0f + logf(dp0 * dp1 * dp2 * dp3) - logdet_q);
    kl_acc += kl;

    float dy0 = y0 - qm0, dy1 = y1 - qm1, dy2 = y2 - qm2;
    float es = -0.5f * (cst + (dy0 * dy0 + qc00) * ine0 +
                        (dy1 * dy1 + qc11) * ine1 + (dy2 * dy2 + qc22) * ine2);
    ell_acc += es;

    // x_new = q_mean + Lq @ eps
    x0r = qm0 + l00 * ev.x;
    x1r = qm1 + l10 * ev.x + l11 * ev.y;
    x2r = qm2 + l20 * ev.x + l21 * ev.y + l22 * ev.z;
    x3r = qm3 + l30 * ev.x + l31 * ev.y + l32 * ev.z + l33 * ev.w;
  }

  if (m == 0) {
    atomicAdd(&acc[2], kl_acc);
    atomicAdd(&acc[3], ell_acc);
  }
}

// ---------------------------------------------------------------------------
__global__ void finalize_kernel(const float* __restrict__ acc, float* __restrict__ out) {
  if (threadIdx.x == 0 && blockIdx.x == 0) {
    float qm0 = acc[0] / 256.0f;
    float gpKL = acc[1];
    float KL = acc[2] / 4096.0f;
    float lik = acc[3] / 4096.0f;
    float e = -qm0 - gpKL + lik - KL;
    if (lik > KL) e = -qm0 - gpKL + lik / 128.0f - KL;
    out[0] = e;
  }
}

// ---------------------------------------------------------------------------
extern "C" void kernel_launch(void* const* d_in, const int* in_sizes, int n_in,
                              void* d_out, int out_size, void* d_ws, size_t ws_size,
                              hipStream_t stream) {
  const float* obs        = (const float*)d_in[0];
  const float* Z          = (const float*)d_in[1];
  const float* log_ls     = (const float*)d_in[2];
  const float* log_os     = (const float*)d_in[3];
  const float* m_u        = (const float*)d_in[4];
  const float* L_u        = (const float*)d_in[5];
  const float* noise_proc = (const float*)d_in[6];
  const float* noise_emis = (const float*)d_in[7];
  const float* Wih        = (const float*)d_in[8];
  const float* Whh        = (const float*)d_in[9];
  const float* b_lstm     = (const float*)d_in[10];
  const float* Wm         = (const float*)d_in[11];
  const float* bm         = (const float*)d_in[12];
  const float* Wv         = (const float*)d_in[13];
  const float* bv         = (const float*)d_in[14];
  const float* W1         = (const float*)d_in[15];
  const float* b1         = (const float*)d_in[16];
  const float* W2         = (const float*)d_in[17];
  const float* b2         = (const float*)d_in[18];
  const float* W3         = (const float*)d_in[19];
  const float* b3         = (const float*)d_in[20];
  const float* W4         = (const float*)d_in[21];
  const float* b4         = (const float*)d_in[22];

  float* ws = (float*)d_ws;
  float* eps0  = ws;                         // 65536
  float* epsU  = eps0 + 65536;               // 2048
  float* epsq  = epsU + 2048;                // 2097152
  float* m0_g  = epsq + 2097152;             // 1024
  float* v0_g  = m0_g + 1024;                // 1024
  float* par_g = v0_g + 1024;                // 1179648
  float* kinvg = par_g + 1179648;            // 4096
  float* alphg = kinvg + 4096;               // 2048
  float* accp  = alphg + 2048;               // 16

  hipMemsetAsync(accp, 0, 64, stream);

  // JAX: rng = key(42) -> (0,42); k0,kU,kq = split(rng,3)
  uint32_t A0, B0, A1, B1, A2, B2;
  threefry2x32(0u, 42u, 0u, 3u, &A0, &B0);
  threefry2x32(0u, 42u, 1u, 4u, &A1, &B1);
  threefry2x32(0u, 42u, 2u, 5u, &A2, &B2);
  const uint32_t k0a = A0, k0b = A1;   // k0
  const uint32_t kUa = A2, kUb = B0;   // kU
  const uint32_t kqa = B1, kqb = B2;   // kq

  // eps0: (16,4,256,4) = 65536
  rng_kernel<<<(32768 + 255) / 256, 256, 0, stream>>>(k0a, k0b, 32768u, eps0);
  // epsU: (16,4,32) = 2048
  rng_kernel<<<(1024 + 255) / 256, 256, 0, stream>>>(kUa, kUb, 1024u, epsU);
  // eps_q: (128,16,256,4) = 2097152
  rng_kernel<<<(1048576 + 255) / 256, 256, 0, stream>>>(kqa, kqb, 1048576u, epsq);

  lstm_kernel<<<BDIM, 256, 0, stream>>>(obs, Wih, Whh, b_lstm, Wm, bm, Wv, bv,
                                        m0_g, v0_g, accp);
  mlp_kernel<<<(BDIM * TLEN) / 16, 256, 0, stream>>>(obs, W1, b1, W2, b2, W3, b3,
                                                     W4, b4, par_g);
  setup_kernel<<<4, 64, 0, stream>>>(Z, log_ls, log_os, m_u, L_u, epsU,
                                     kinvg, alphg, accp);
  scan_kernel<<<512, 256, 0, stream>>>(Z, log_ls, log_os, noise_proc, noise_emis,
                                       obs, par_g, m0_g, v0_g, eps0, epsq,
                                       kinvg, alphg, accp);
  finalize_kernel<<<1, 64, 0, stream>>>(accp, (float*)d_out);
}

// Round 2
// 756.293 us; speedup vs baseline: 1.7830x; 1.7830x over previous
//
#include <hip/hip_runtime.h>
#include <cstdint>
#include <math.h>

// Problem constants
#define NMC   16
#define SDIM  4
#define ODIM  3
#define TLEN  128
#define BDIM  256
#define MDIM  32
#define HLDIM 64
#define PARD  36

#define LOG2PI_F 1.8378770664093453f

// ---------------------------------------------------------------------------
// threefry2x32 (JAX-compatible, 20 rounds)
// ---------------------------------------------------------------------------
__host__ __device__ inline void threefry2x32(uint32_t k0, uint32_t k1,
                                             uint32_t x0, uint32_t x1,
                                             uint32_t* o0, uint32_t* o1) {
  uint32_t ks0 = k0, ks1 = k1, ks2 = k0 ^ k1 ^ 0x1BD11BDAu;
  x0 += ks0; x1 += ks1;
#define TF_R(r) { x0 += x1; x1 = (x1 << (r)) | (x1 >> (32 - (r))); x1 ^= x0; }
  TF_R(13) TF_R(15) TF_R(26) TF_R(6)  x0 += ks1; x1 += ks2 + 1u;
  TF_R(17) TF_R(29) TF_R(16) TF_R(24) x0 += ks2; x1 += ks0 + 2u;
  TF_R(13) TF_R(15) TF_R(26) TF_R(6)  x0 += ks0; x1 += ks1 + 3u;
  TF_R(17) TF_R(29) TF_R(16) TF_R(24) x0 += ks1; x1 += ks2 + 4u;
  TF_R(13) TF_R(15) TF_R(26) TF_R(6)  x0 += ks2; x1 += ks0 + 5u;
#undef TF_R
  *o0 = x0; *o1 = x1;
}

// XLA f32 ErfInv polynomial
__device__ inline float erfinv_f32(float x) {
  float w = -log1pf(-x * x);
  float p;
  if (w < 5.0f) {
    w -= 2.5f;
    p = 2.81022636e-08f;
    p = fmaf(p, w, 3.43273939e-07f);
    p = fmaf(p, w, -3.5233877e-06f);
    p = fmaf(p, w, -4.39150654e-06f);
    p = fmaf(p, w, 0.00021858087f);
    p = fmaf(p, w, -0.00125372503f);
    p = fmaf(p, w, -0.00417768164f);
    p = fmaf(p, w, 0.246640727f);
    p = fmaf(p, w, 1.50140941f);
  } else {
    w = sqrtf(w) - 3.0f;
    p = -0.000200214257f;
    p = fmaf(p, w, 0.000100950558f);
    p = fmaf(p, w, 0.00134934322f);
    p = fmaf(p, w, -0.00367342844f);
    p = fmaf(p, w, 0.00573950773f);
    p = fmaf(p, w, -0.0076224613f);
    p = fmaf(p, w, 0.00943887047f);
    p = fmaf(p, w, 1.00167406f);
    p = fmaf(p, w, 2.83297682f);
  }
  return p * x;
}

__device__ inline float bits_to_normal(uint32_t b) {
  float f = __uint_as_float((b >> 9) | 0x3F800000u) - 1.0f;  // [0,1)
  const float lo = -0.99999994f;
  float u = f * 2.0f + lo;
  u = fmaxf(lo, u);
  return 1.41421356f * erfinv_f32(u);
}

__global__ void rng_kernel(uint32_t ka, uint32_t kb, uint32_t nhalf, float* out) {
  uint32_t j = blockIdx.x * blockDim.x + threadIdx.x;
  if (j >= nhalf) return;
  uint32_t o0, o1;
  threefry2x32(ka, kb, j, j + nhalf, &o0, &o1);
  out[j] = bits_to_normal(o0);
  out[j + nhalf] = bits_to_normal(o1);
}

// ---------------------------------------------------------------------------
// DPP-based allreduce over 32 lanes (two 16-rows + one xor-16 swizzle).
// row_ror within 16 is VALU-rate; only 1 DS op per reduction.
// ---------------------------------------------------------------------------
#define DPP_ROR_ADD(v, ctrl) \
  ((v) + __int_as_float(__builtin_amdgcn_update_dpp(0, __float_as_int(v), (ctrl), 0xf, 0xf, false)))

__device__ __forceinline__ float allred32(float v) {
  v = DPP_ROR_ADD(v, 0x128);  // row_ror:8
  v = DPP_ROR_ADD(v, 0x124);  // row_ror:4
  v = DPP_ROR_ADD(v, 0x122);  // row_ror:2
  v = DPP_ROR_ADD(v, 0x121);  // row_ror:1  -> all 16 lanes hold row sum
  return v + __shfl_xor(v, 16);
}

__device__ __forceinline__ float sigm_fast(float x) {
  return 1.0f / (1.0f + __expf(-x));
}
__device__ __forceinline__ float tanh_fast(float x) {
  // 1 - 2/(1+e^{2x}); saturates correctly at +/-1
  return 1.0f - 2.0f / (1.0f + __expf(2.0f * x));
}

// ---------------------------------------------------------------------------
// LSTM: block = batch row b, 4 waves; wave w owns gate type w (rows 64w..64w+63).
// h replicated per wave in private LDS buffer (no barrier for h); g exchanged
// via double-buffered LDS -> ONE barrier per step.
// ---------------------------------------------------------------------------
__global__ __launch_bounds__(256) void lstm_kernel(
    const float* __restrict__ obs, const float* __restrict__ Wih,
    const float* __restrict__ Whh, const float* __restrict__ b_lstm,
    const float* __restrict__ Wm, const float* __restrict__ bm,
    const float* __restrict__ Wv, const float* __restrict__ bv,
    float* __restrict__ m0_g, float* __restrict__ v0_g, float* __restrict__ acc) {
  __shared__ float g_l[2][4][64];
  __shared__ float h_w[4][64];
  __shared__ float mv_l[8];
  const int tid = threadIdx.x;
  const int w = tid >> 6;
  const int l = tid & 63;
  const int b = blockIdx.x;

  float whh_r[64];
  {
    const float4* wsrc = (const float4*)(Whh + tid * 64);
#pragma unroll
    for (int q = 0; q < 16; ++q) {
      float4 v = wsrc[q];
      whh_r[q * 4 + 0] = v.x; whh_r[q * 4 + 1] = v.y;
      whh_r[q * 4 + 2] = v.z; whh_r[q * 4 + 3] = v.w;
    }
  }
  const float wih0 = Wih[tid * 3 + 0];
  const float wih1 = Wih[tid * 3 + 1];
  const float wih2 = Wih[tid * 3 + 2];
  const float bb = b_lstm[tid];

  float c_ = 0.0f;
  h_w[w][l] = 0.0f;  // own wave's buffer; same-wave visibility via lgkmcnt

  const float* ob = obs + b * TLEN * ODIM;
#pragma unroll 1
  for (int t = 0; t < TLEN; ++t) {
    const float x0 = ob[t * 3 + 0], x1 = ob[t * 3 + 1], x2 = ob[t * 3 + 2];
    const float4* h4 = (const float4*)&h_w[w][0];
    float a0 = 0.f, a1 = 0.f, a2 = 0.f, a3 = 0.f;
#pragma unroll
    for (int q = 0; q < 16; ++q) {
      float4 hv = h4[q];
      a0 = fmaf(whh_r[q * 4 + 0], hv.x, a0);
      a1 = fmaf(whh_r[q * 4 + 1], hv.y, a1);
      a2 = fmaf(whh_r[q * 4 + 2], hv.z, a2);
      a3 = fmaf(whh_r[q * 4 + 3], hv.w, a3);
    }
    float g = fmaf(wih0, x0, fmaf(wih1, x1, fmaf(wih2, x2, bb))) + ((a0 + a1) + (a2 + a3));
    g_l[t & 1][w][l] = g;
    __syncthreads();
    float gi = g_l[t & 1][0][l];
    float gf = g_l[t & 1][1][l];
    float gg = g_l[t & 1][2][l];
    float go = g_l[t & 1][3][l];
    c_ = sigm_fast(gf) * c_ + sigm_fast(gi) * tanh_fast(gg);
    h_w[w][l] = sigm_fast(go) * tanh_fast(c_);
  }

  // epilogue entirely within wave 0 (reads wave 0's h buffer)
  if (tid < 8) {
    const int s = tid & 3;
    const bool isv = tid >= 4;
    const float* W = isv ? (Wv + s * 64) : (Wm + s * 64);
    float a = isv ? bv[s] : bm[s];
#pragma unroll
    for (int k = 0; k < 64; ++k) a += W[k] * h_w[0][k];
    if (!isv) {
      m0_g[b * 4 + s] = a;
      mv_l[s] = a;
    } else {
      float sp = (a > 0.f) ? (a + log1pf(expf(-a))) : log1pf(expf(a));
      float v = sp + 1e-6f;
      v0_g[b * 4 + s] = v;
      mv_l[4 + s] = v;
    }
  }
  if (tid == 0) {
    float s = 0.f;
#pragma unroll
    for (int k = 0; k < 4; ++k) {
      float m = mv_l[k], v = mv_l[4 + k];
      s += 0.5f * (v + m * m - 1.0f - logf(v));
    }
    atomicAdd(&acc[0], s);
  }
}

// ---------------------------------------------------------------------------
// MLP as fused LDS-staged register-tile GEMM.
// 512 blocks x 256 threads, 64 rows/block.
// Layer2: micro-tile 4r x 8j, W2 staged k-major in 4 K-chunks of 64;
// h1 computed on the fly per chunk (never materialized in full).
// Layer3: 4r x 4j, W3 staged in 2 K-chunks. Layer4 via scalar W4 loads.
// ---------------------------------------------------------------------------
#define MLP_SB 128
__global__ __launch_bounds__(256) void mlp_kernel(
    const float* __restrict__ obs, const float* __restrict__ W1, const float* __restrict__ b1,
    const float* __restrict__ W2, const float* __restrict__ b2,
    const float* __restrict__ W3, const float* __restrict__ b3,
    const float* __restrict__ W4, const float* __restrict__ b4,
    float* __restrict__ par_g) {
  __shared__ float xs[3][64];
  __shared__ float A_l[64 * 64];       // [k][r] (also W3T chunk, then H3 [j][r])
  __shared__ float B_l[64 * MLP_SB];   // [k][j] W2T chunk (also H2 [j][r])
  const int tid = threadIdx.x;
  const int R0 = blockIdx.x * 64;
  const int tr = tid & 15;             // 16 r-groups of 4
  const int tj = tid >> 4;             // 16 j-groups

  for (int idx = tid; idx < 192; idx += 256) {
    int r = idx & 63, o = idx >> 6;
    xs[o][r] = obs[(R0 + r) * 3 + o];
  }

  // ---------------- layers 1+2 ----------------
  float acc2[4][8];
#pragma unroll
  for (int i = 0; i < 4; ++i)
#pragma unroll
    for (int j = 0; j < 8; ++j) acc2[i][j] = 0.f;

  for (int kc = 0; kc < 4; ++kc) {
    __syncthreads();  // protects B_l/A_l reuse (and xs on first pass)
    {  // stage W2 chunk transposed: B_l[k][j] = W2[j][kc*64+k]
      int j = tid & 127, kh = (tid >> 7) * 32;
      const float4* wsrc = (const float4*)(W2 + j * 256 + kc * 64 + kh);
#pragma unroll
      for (int q = 0; q < 8; ++q) {
        float4 v = wsrc[q];
        int k = kh + q * 4;
        B_l[(k + 0) * MLP_SB + j] = v.x;
        B_l[(k + 1) * MLP_SB + j] = v.y;
        B_l[(k + 2) * MLP_SB + j] = v.z;
        B_l[(k + 3) * MLP_SB + j] = v.w;
      }
    }
    {  // layer1 on the fly: A_l[k][r] = relu(b1 + W1 x_r), k in chunk
      int r = tid & 63, q4 = tid >> 6;
      float x0 = xs[0][r], x1 = xs[1][r], x2 = xs[2][r];
      const float4* w1p = (const float4*)(W1 + (kc * 64 + q4 * 16) * 3);
      float4 wv[12];
#pragma unroll
      for (int q = 0; q < 12; ++q) wv[q] = w1p[q];
      const float* wf = (const float*)wv;
#pragma unroll
      for (int i = 0; i < 16; ++i) {
        int k = q4 * 16 + i;
        float v = b1[kc * 64 + k] + wf[i * 3] * x0 + wf[i * 3 + 1] * x1 + wf[i * 3 + 2] * x2;
        A_l[k * 64 + r] = fmaxf(v, 0.f);
      }
    }
    __syncthreads();
    for (int k = 0; k < 64; ++k) {
      float4 av = *(const float4*)&A_l[k * 64 + tr * 4];
      float4 b0 = *(const float4*)&B_l[k * MLP_SB + tj * 8];
      float4 b1v = *(const float4*)&B_l[k * MLP_SB + tj * 8 + 4];
      const float a4[4] = {av.x, av.y, av.z, av.w};
      const float bv8[8] = {b0.x, b0.y, b0.z, b0.w, b1v.x, b1v.y, b1v.z, b1v.w};
#pragma unroll
      for (int ri = 0; ri < 4; ++ri)
#pragma unroll
        for (int ji = 0; ji < 8; ++ji)
          acc2[ri][ji] = fmaf(a4[ri], bv8[ji], acc2[ri][ji]);
    }
  }
  __syncthreads();  // all B_l reads done; safe to overwrite as H2
  // h2 -> B_l as [j][r] (k-major for layer3)
#pragma unroll
  for (int ji = 0; ji < 8; ++ji) {
    int j = tj * 8 + ji;
    float bias = b2[j];
    float4 hv;
    hv.x = fmaxf(acc2[0][ji] + bias, 0.f);
    hv.y = fmaxf(acc2[1][ji] + bias, 0.f);
    hv.z = fmaxf(acc2[2][ji] + bias, 0.f);
    hv.w = fmaxf(acc2[3][ji] + bias, 0.f);
    *(float4*)&B_l[j * 64 + tr * 4] = hv;
  }

  // ---------------- layer 3 ----------------
  float acc3[4][4];
#pragma unroll
  for (int i = 0; i < 4; ++i)
#pragma unroll
    for (int j = 0; j < 4; ++j) acc3[i][j] = 0.f;

  for (int kc = 0; kc < 2; ++kc) {
    __syncthreads();  // protects A_l reuse + H2 visibility on first pass
    {  // stage W3T chunk into A_l[k][j]
      int j = tid & 63, kq = (tid >> 6) * 16;
      const float4* wsrc = (const float4*)(W3 + j * 128 + kc * 64 + kq);
#pragma unroll
      for (int q = 0; q < 4; ++q) {
        float4 v = wsrc[q];
        int k = kq + q * 4;
        A_l[(k + 0) * 64 + j] = v.x;
        A_l[(k + 1) * 64 + j] = v.y;
        A_l[(k + 2) * 64 + j] = v.z;
        A_l[(k + 3) * 64 + j] = v.w;
      }
    }
    __syncthreads();
    for (int k = 0; k < 64; ++k) {
      float4 av = *(const float4*)&B_l[(kc * 64 + k) * 64 + tr * 4];  // H2
      float4 bv = *(const float4*)&A_l[k * 64 + (tj & 15) * 4];       // W3T
      const float a4[4] = {av.x, av.y, av.z, av.w};
      const float b4v[4] = {bv.x, bv.y, bv.z, bv.w};
#pragma unroll
      for (int ri = 0; ri < 4; ++ri)
#pragma unroll
        for (int ji = 0; ji < 4; ++ji)
          acc3[ri][ji] = fmaf(a4[ri], b4v[ji], acc3[ri][ji]);
    }
  }
  __syncthreads();  // A_l reads done; reuse as H3
#pragma unroll
  for (int ji = 0; ji < 4; ++ji) {
    int j = tj * 4 + ji;
    float bias = b3[j];
    float4 hv;
    hv.x = fmaxf(acc3[0][ji] + bias, 0.f);
    hv.y = fmaxf(acc3[1][ji] + bias, 0.f);
    hv.z = fmaxf(acc3[2][ji] + bias, 0.f);
    hv.w = fmaxf(acc3[3][ji] + bias, 0.f);
    *(float4*)&A_l[j * 64 + tr * 4] = hv;
  }
  __syncthreads();

  // ---------------- layer 4 ----------------
  {
    int r = tid & 63;
    int jg = __builtin_amdgcn_readfirstlane(tid >> 6);  // wave-uniform -> scalar W4 loads
    float accp[9];
#pragma unroll
    for (int i = 0; i < 9; ++i) accp[i] = b4[jg * 9 + i];
    for (int k = 0; k < 64; ++k) {
      float hv = A_l[k * 64 + r];
#pragma unroll
      for (int i = 0; i < 9; ++i)
        accp[i] = fmaf(hv, W4[(jg * 9 + i) * 64 + k], accp[i]);
    }
#pragma unroll
    for (int i = 0; i < 9; ++i) par_g[(R0 + r) * 36 + jg * 9 + i] = accp[i];
  }
}

// ---------------------------------------------------------------------------
// Setup: per d (4 blocks, 64 threads): Kzz -> chol L -> Kinv; U -> alpha;
// gpKL partial (acc[1]).
// ---------------------------------------------------------------------------
__global__ __launch_bounds__(64) void setup_kernel(
    const float* __restrict__ Z, const float* __restrict__ log_ls,
    const float* __restrict__ log_os, const float* __restrict__ m_u,
    const float* __restrict__ L_u, const float* __restrict__ epsU,
    float* __restrict__ Kinv_g, float* __restrict__ alpha_g, float* __restrict__ acc) {
  const int d = blockIdx.x;
  const int tid = threadIdx.x;
  __shared__ float Kl[32][33];
  __shared__ float work[32][33];
  __shared__ float Ul[16][32];
  __shared__ float bql[32];
  __shared__ float red[64];

  float il[4];
#pragma unroll
  for (int k = 0; k < 4; ++k) il[k] = expf(-log_ls[d * 4 + k]);
  const float osd = expf(log_os[d]);

  for (int e = tid; e < 1024; e += 64) {
    int i = e >> 5, j = e & 31;
    float s = 0.f;
#pragma unroll
    for (int k = 0; k < 4; ++k) {
      float t_ = (Z[d * 128 + i * 4 + k] - Z[d * 128 + j * 4 + k]) * il[k];
      s += t_ * t_;
    }
    float v = osd * expf(-0.5f * s);
    if (i == j) v += 1e-5f;
    Kl[i][j] = v;
  }
  __syncthreads();

  for (int jc = 0; jc < 32; ++jc) {
    if (tid == jc) {
      float s = Kl[jc][jc];
      for (int p = 0; p < jc; ++p) s -= Kl[jc][p] * Kl[jc][p];
      Kl[jc][jc] = sqrtf(s);
    }
    __syncthreads();
    if (tid > jc && tid < 32) {
      float s = Kl[tid][jc];
      for (int p = 0; p < jc; ++p) s -= Kl[tid][p] * Kl[jc][p];
      Kl[tid][jc] = s / Kl[jc][jc];
    }
    __syncthreads();
  }

  if (tid < 32) {
    const int col = tid;
    for (int r = 0; r < 32; ++r) {
      if (r < col) { work[col][r] = 0.f; continue; }
      float s = (r == col) ? 1.f : 0.f;
      for (int p = col; p < r; ++p) s -= Kl[r][p] * work[col][p];
      work[col][r] = s / Kl[r][r];
    }
    for (int r = 31; r >= 0; --r) {
      float s = work[col][r];
      for (int p = r + 1; p < 32; ++p) s -= Kl[p][r] * work[col][p];
      work[col][r] = s / Kl[r][r];
    }
    for (int r = 0; r < 32; ++r) Kinv_g[(d * 32 + r) * 32 + col] = work[col][r];
  }
  for (int e = tid; e < 512; e += 64) {
    int nn = e >> 5, m = e & 31;
    float s = m_u[d * 32 + m];
    for (int k = 0; k <= m; ++k)
      s += L_u[(d * 32 + m) * 32 + k] * epsU[(nn * 4 + d) * 32 + k];
    Ul[nn][m] = s;
  }
  __syncthreads();
  for (int e = tid; e < 512; e += 64) {
    int nn = e >> 5, m = e & 31;
    float s = 0.f;
    for (int mm = 0; mm < 32; ++mm) s += work[mm][m] * Ul[nn][mm];
    alpha_g[(d * 16 + nn) * 32 + m] = s;
  }
  __syncthreads();

  float contrib = 0.f;
  if (tid < 32) {
    const int col = tid;
    float sa = 0.f;
    for (int r = 0; r < 32; ++r) {
      float s = (col <= r) ? L_u[(d * 32 + r) * 32 + col] : 0.f;
      for (int p = 0; p < r; ++p) s -= Kl[r][p] * work[col][p];
      float v = s / Kl[r][r];
      work[col][r] = v;
      sa += v * v;
    }
    contrib = sa;
  } else if (tid == 32) {
    float sb = 0.f;
    for (int r = 0; r < 32; ++r) {
      float s = m_u[d * 32 + r];
      for (int p = 0; p < r; ++p) s -= Kl[r][p] * bql[p];
      float v = s / Kl[r][r];
      bql[r] = v;
      sb += v * v;
    }
    contrib = sb;
  }
  red[tid] = contrib;
  __syncthreads();
  if (tid == 0) {
    float s = 0.f;
    for (int i = 0; i < 64; ++i) s += red[i];
    float ldK = 0.f, ldS = 0.f;
    for (int r = 0; r < 32; ++r) {
      ldK += logf(Kl[r][r]);
      ldS += logf(fabsf(L_u[(d * 32 + r) * 32 + r]) + 1e-12f);
    }
    float g = s - 32.0f + 2.0f * ldK - 2.0f * ldS;
    atomicAdd(&acc[1], 0.5f * g / (128.0f * 256.0f));
  }
}

// ---------------------------------------------------------------------------
// Scan: 4096 independent chains; 32 lanes/chain (chain = half-wave).
// kbuf is half-wave-private -> NO barriers. Reductions via DPP + 1 swizzle.
// ---------------------------------------------------------------------------
__global__ __launch_bounds__(256, 2) void scan_kernel(
    const float* __restrict__ Z, const float* __restrict__ log_ls,
    const float* __restrict__ log_os, const float* __restrict__ noise_proc,
    const float* __restrict__ noise_emis, const float* __restrict__ obs,
    const float* __restrict__ par_g, const float* __restrict__ m0_g,
    const float* __restrict__ v0_g, const float* __restrict__ eps0,
    const float* __restrict__ epsq, const float* __restrict__ Kinv_g,
    const float* __restrict__ alpha_g, float* __restrict__ acc) {
  __shared__ float kbuf[8][4][32];
  const int tid = threadIdx.x;
  const int c = tid >> 5;
  const int m = tid & 31;
  const int b = blockIdx.x >> 1;
  const int n = ((blockIdx.x & 1) << 3) + c;

  float zr[4][4], ilr[4][4], osr[4];
#pragma unroll
  for (int d = 0; d < 4; ++d) {
#pragma unroll
    for (int k = 0; k < 4; ++k) {
      zr[d][k] = Z[d * 128 + m * 4 + k];
      ilr[d][k] = expf(-log_ls[d * 4 + k]);
    }
    osr[d] = expf(log_os[d]);
  }
  float kinv[4][32];
  {
    const float4* kg4 = (const float4*)Kinv_g;
#pragma unroll
    for (int d = 0; d < 4; ++d) {
#pragma unroll
      for (int q = 0; q < 8; ++q) {
        float4 v = kg4[(d * 32 + m) * 8 + q];
        kinv[d][q * 4 + 0] = v.x;
        kinv[d][q * 4 + 1] = v.y;
        kinv[d][q * 4 + 2] = v.z;
        kinv[d][q * 4 + 3] = v.w;
      }
    }
  }
  float alr[4];
#pragma unroll
  for (int d = 0; d < 4; ++d) alr[d] = alpha_g[(d * 16 + n) * 32 + m];
  float np_[4];
#pragma unroll
  for (int k = 0; k < 4; ++k) np_[k] = noise_proc[k];
  float ine0 = 1.0f / noise_emis[0], ine1 = 1.0f / noise_emis[1], ine2 = 1.0f / noise_emis[2];
  const float cst = 3.0f * LOG2PI_F + logf(noise_emis[0]) + logf(noise_emis[1]) + logf(noise_emis[2]);

  const float* parb = par_g + b * TLEN * PARD;
  const float* obsb = obs + b * TLEN * ODIM;

  float x0r = 0.f, x1r = 0.f, x2r = 0.f, x3r = 0.f;
  float kl_acc = 0.f, ell_acc = 0.f;

#pragma unroll 1
  for (int t = 0; t < TLEN; ++t) {
    const float4* pv = (const float4*)(parb + t * PARD);
    const float4 a0 = pv[0], a1 = pv[1], a2 = pv[2], a3 = pv[3];
    const float4 btv = pv[4];
    const float4 s0 = pv[5], s1 = pv[6], s2 = pv[7], s3 = pv[8];
    const float y0 = obsb[t * 3 + 0], y1 = obsb[t * 3 + 1], y2 = obsb[t * 3 + 2];
    const float4 ev = *(const float4*)(epsq + (((t * 16 + n) * 256 + b) << 2));

    // phase 1: RBF features
    float kreg[4];
#pragma unroll
    for (int d = 0; d < 4; ++d) {
      float xt0, xt1, xt2, xt3;
      if (t == 0) {
        const int e0i = ((n * 4 + d) * 256 + b) * 4;
        xt0 = m0_g[b * 4 + 0] + sqrtf(v0_g[b * 4 + 0]) * eps0[e0i + 0];
        xt1 = m0_g[b * 4 + 1] + sqrtf(v0_g[b * 4 + 1]) * eps0[e0i + 1];
        xt2 = m0_g[b * 4 + 2] + sqrtf(v0_g[b * 4 + 2]) * eps0[e0i + 2];
        xt3 = m0_g[b * 4 + 3] + sqrtf(v0_g[b * 4 + 3]) * eps0[e0i + 3];
      } else {
        xt0 = x0r; xt1 = x1r; xt2 = x2r; xt3 = x3r;
      }
      float d0_ = (xt0 - zr[d][0]) * ilr[d][0];
      float d1_ = (xt1 - zr[d][1]) * ilr[d][1];
      float d2_ = (xt2 - zr[d][2]) * ilr[d][2];
      float d3_ = (xt3 - zr[d][3]) * ilr[d][3];
      float ss = d0_ * d0_ + d1_ * d1_ + d2_ * d2_ + d3_ * d3_;
      float km = osr[d] * __expf(-0.5f * ss);
      kreg[d] = km;
      kbuf[c][d][m] = km;  // half-wave private; no barrier needed
    }

    // phase 2: mean / quad form (LDS broadcast reads, same-wave ordering)
    float gm[4], gv[4];
#pragma unroll
    for (int d = 0; d < 4; ++d) {
      const float4* kb4 = (const float4*)&kbuf[c][d][0];
      float ya = 0.f, yb = 0.f, yc = 0.f, yd = 0.f;
#pragma unroll
      for (int q = 0; q < 8; ++q) {
        float4 kv = kb4[q];
        ya = fmaf(kinv[d][q * 4 + 0], kv.x, ya);
        yb = fmaf(kinv[d][q * 4 + 1], kv.y, yb);
        yc = fmaf(kinv[d][q * 4 + 2], kv.z, yc);
        yd = fmaf(kinv[d][q * 4 + 3], kv.w, yd);
      }
      float y = (ya + yb) + (yc + yd);
      gm[d] = allred32(kreg[d] * alr[d]);
      float qp = allred32(kreg[d] * y);
      gv[d] = fmaxf(osr[d] - qp, 1e-8f);
    }

    // tail (redundant on the 32 lanes of the chain)
    float qm0 = btv.x + a0.x * gm[0] + a0.y * gm[1] + a0.z * gm[2] + a0.w * gm[3];
    float qm1 = btv.y + a1.x * gm[0] + a1.y * gm[1] + a1.z * gm[2] + a1.w * gm[3];
    float qm2 = btv.z + a2.x * gm[0] + a2.y * gm[1] + a2.z * gm[2] + a2.w * gm[3];
    float qm3 = btv.w + a3.x * gm[0] + a3.y * gm[1] + a3.z * gm[2] + a3.w * gm[3];

    float St00 = s0.x * s0.x;
    float St10 = s1.x * s0.x;
    float St11 = s1.x * s1.x + s1.y * s1.y;
    float St20 = s2.x * s0.x;
    float St21 = s2.x * s1.x + s2.y * s1.y;
    float St22 = s2.x * s2.x + s2.y * s2.y + s2.z * s2.z;
    float St30 = s3.x * s0.x;
    float St31 = s3.x * s1.x + s3.y * s1.y;
    float St32 = s3.x * s2.x + s3.y * s2.y + s3.z * s2.z;
    float St33 = s3.x * s3.x + s3.y * s3.y + s3.z * s3.z + s3.w * s3.w;

    float w0x = a0.x * gv[0], w0y = a0.y * gv[1], w0z = a0.z * gv[2], w0w = a0.w * gv[3];
    float w1x = a1.x * gv[0], w1y = a1.y * gv[1], w1z = a1.z * gv[2], w1w = a1.w * gv[3];
    float w2x = a2.x * gv[0], w2y = a2.y * gv[1], w2z = a2.z * gv[2], w2w = a2.w * gv[3];
    float w3x = a3.x * gv[0], w3y = a3.y * gv[1], w3z = a3.z * gv[2], w3w = a3.w * gv[3];
    float qc00 = St00 + w0x * a0.x + w0y * a0.y + w0z * a0.z + w0w * a0.w;
    float qc10 = St10 + w1x * a0.x + w1y * a0.y + w1z * a0.z + w1w * a0.w;
    float qc11 = St11 + w1x * a1.x + w1y * a1.y + w1z * a1.z + w1w * a1.w;
    float qc20 = St20 + w2x * a0.x + w2y * a0.y + w2z * a0.z + w2w * a0.w;
    float qc21 = St21 + w2x * a1.x + w2y * a1.y + w2z * a1.z + w2w * a1.w;
    float qc22 = St22 + w2x * a2.x + w2y * a2.y + w2z * a2.z + w2w * a2.w;
    float qc30 = St30 + w3x * a0.x + w3y * a0.y + w3z * a0.z + w3w * a0.w;
    float qc31 = St31 + w3x * a1.x + w3y * a1.y + w3z * a1.z + w3w * a1.w;
    float qc32 = St32 + w3x * a2.x + w3y * a2.y + w3z * a2.z + w3w * a2.w;
    float qc33 = St33 + w3x * a3.x + w3y * a3.y + w3z * a3.z + w3w * a3.w;

    float l00 = sqrtf(qc00 + 1e-6f);
    float i0 = 1.0f / l00;
    float l10 = qc10 * i0, l20 = qc20 * i0, l30 = qc30 * i0;
    float l11 = sqrtf(qc11 + 1e-6f - l10 * l10);
    float i1 = 1.0f / l11;
    float l21 = (qc21 - l20 * l10) * i1;
    float l31 = (qc31 - l30 * l10) * i1;
    float l22 = sqrtf(qc22 + 1e-6f - l20 * l20 - l21 * l21);
    float i2 = 1.0f / l22;
    float l32 = (qc32 - l30 * l20 - l31 * l21) * i2;
    float l33 = sqrtf(qc33 + 1e-6f - l30 * l30 - l31 * l31 - l32 * l32);
    float logdet_q = 2.0f * __logf(l00 * l11 * l22 * l33);

    float dp0 = gv[0] + np_[0], dp1 = gv[1] + np_[1];
    float dp2 = gv[2] + np_[2], dp3 = gv[3] + np_[3];
    float e0 = gm[0] - qm0, e1 = gm[1] - qm1, e2 = gm[2] - qm2, e3 = gm[3] - qm3;
    float klsum = (qc00 + e0 * e0) / dp0 + (qc11 + e1 * e1) / dp1 +
                  (qc22 + e2 * e2) / dp2 + (qc33 + e3 * e3) / dp3;
    float kl = 0.5f * (klsum - 4.0f + __logf(dp0 * dp1 * dp2 * dp3) - logdet_q);
    kl_acc += kl;

    float dy0 = y0 - qm0, dy1 = y1 - qm1, dy2 = y2 - qm2;
    float es = -0.5f * (cst + (dy0 * dy0 + qc00) * ine0 +
                        (dy1 * dy1 + qc11) * ine1 + (dy2 * dy2 + qc22) * ine2);
    ell_acc += es;

    x0r = qm0 + l00 * ev.x;
    x1r = qm1 + l10 * ev.x + l11 * ev.y;
    x2r = qm2 + l20 * ev.x + l21 * ev.y + l22 * ev.z;
    x3r = qm3 + l30 * ev.x + l31 * ev.y + l32 * ev.z + l33 * ev.w;
  }

  if (m == 0) {
    atomicAdd(&acc[2], kl_acc);
    atomicAdd(&acc[3], ell_acc);
  }
}

// ---------------------------------------------------------------------------
__global__ void finalize_kernel(const float* __restrict__ acc, float* __restrict__ out) {
  if (threadIdx.x == 0 && blockIdx.x == 0) {
    float qm0 = acc[0] / 256.0f;
    float gpKL = acc[1];
    float KL = acc[2] / 4096.0f;
    float lik = acc[3] / 4096.0f;
    float e = -qm0 - gpKL + lik - KL;
    if (lik > KL) e = -qm0 - gpKL + lik / 128.0f - KL;
    out[0] = e;
  }
}

// ---------------------------------------------------------------------------
extern "C" void kernel_launch(void* const* d_in, const int* in_sizes, int n_in,
                              void* d_out, int out_size, void* d_ws, size_t ws_size,
                              hipStream_t stream) {
  const float* obs        = (const float*)d_in[0];
  const float* Z          = (const float*)d_in[1];
  const float* log_ls     = (const float*)d_in[2];
  const float* log_os     = (const float*)d_in[3];
  const float* m_u        = (const float*)d_in[4];
  const float* L_u        = (const float*)d_in[5];
  const float* noise_proc = (const float*)d_in[6];
  const float* noise_emis = (const float*)d_in[7];
  const float* Wih        = (const float*)d_in[8];
  const float* Whh        = (const float*)d_in[9];
  const float* b_lstm     = (const float*)d_in[10];
  const float* Wm         = (const float*)d_in[11];
  const float* bm         = (const float*)d_in[12];
  const float* Wv         = (const float*)d_in[13];
  const float* bv         = (const float*)d_in[14];
  const float* W1         = (const float*)d_in[15];
  const float* b1         = (const float*)d_in[16];
  const float* W2         = (const float*)d_in[17];
  const float* b2         = (const float*)d_in[18];
  const float* W3         = (const float*)d_in[19];
  const float* b3         = (const float*)d_in[20];
  const float* W4         = (const float*)d_in[21];
  const float* b4         = (const float*)d_in[22];

  float* ws = (float*)d_ws;
  float* eps0  = ws;                         // 65536
  float* epsU  = eps0 + 65536;               // 2048
  float* epsq  = epsU + 2048;                // 2097152
  float* m0_g  = epsq + 2097152;             // 1024
  float* v0_g  = m0_g + 1024;                // 1024
  float* par_g = v0_g + 1024;                // 1179648
  float* kinvg = par_g + 1179648;            // 4096
  float* alphg = kinvg + 4096;               // 2048
  float* accp  = alphg + 2048;               // 16

  hipMemsetAsync(accp, 0, 64, stream);

  uint32_t A0, B0, A1, B1, A2, B2;
  threefry2x32(0u, 42u, 0u, 3u, &A0, &B0);
  threefry2x32(0u, 42u, 1u, 4u, &A1, &B1);
  threefry2x32(0u, 42u, 2u, 5u, &A2, &B2);
  const uint32_t k0a = A0, k0b = A1;   // k0
  const uint32_t kUa = A2, kUb = B0;   // kU
  const uint32_t kqa = B1, kqb = B2;   // kq

  rng_kernel<<<(32768 + 255) / 256, 256, 0, stream>>>(k0a, k0b, 32768u, eps0);
  rng_kernel<<<(1024 + 255) / 256, 256, 0, stream>>>(kUa, kUb, 1024u, epsU);
  rng_kernel<<<(1048576 + 255) / 256, 256, 0, stream>>>(kqa, kqb, 1048576u, epsq);

  lstm_kernel<<<BDIM, 256, 0, stream>>>(obs, Wih, Whh, b_lstm, Wm, bm, Wv, bv,
                                        m0_g, v0_g, accp);
  mlp_kernel<<<512, 256, 0, stream>>>(obs, W1, b1, W2, b2, W3, b3,
                                      W4, b4, par_g);
  setup_kernel<<<4, 64, 0, stream>>>(Z, log_ls, log_os, m_u, L_u, epsU,
                                     kinvg, alphg, accp);
  scan_kernel<<<512, 256, 0, stream>>>(Z, log_ls, log_os, noise_proc, noise_emis,
                                       obs, par_g, m0_g, v0_g, eps0, epsq,
                                       kinvg, alphg, accp);
  finalize_kernel<<<1, 64, 0, stream>>>(accp, (float*)d_out);
}